// Round 6
// baseline (155.533 us; speedup 1.0000x reference)
//
#include <hip/hip_runtime.h>
#include <stdint.h>

typedef float  f32x4  __attribute__((ext_vector_type(4)));
typedef short  bf16x8 __attribute__((ext_vector_type(8)));
typedef unsigned short u16;
typedef u16    u16x4  __attribute__((ext_vector_type(4)));

#define HD 16   // heads
#define DD 64   // head dim
#define BQ 64   // q rows per block
#define BK 64   // keys per LDS tile

__device__ __forceinline__ u16 f2bf(float f) {
  uint32_t u = __float_as_uint(f);
  u = (u + 0x7FFFu + ((u >> 16) & 1u)) >> 16;   // round-to-nearest-even
  return (u16)u;
}

// swizzled LDS vector read: row-major [R][64] bf16, idx ^= (row&7)<<3 (elements)
__device__ __forceinline__ bf16x8 ldsw8(const u16* base, int row, int col) {
  int idx = (row * 64 + col) ^ ((row & 7) << 3);
  return *reinterpret_cast<const bf16x8*>(base + idx);
}

__global__ __launch_bounds__(256) void fa_fwd(
    const float* __restrict__ q, const float* __restrict__ k,
    const float* __restrict__ v, const int* __restrict__ cu,
    float* __restrict__ out, int T, int nseq)
{
  __shared__ __align__(16) u16 sKhi[BK * DD];
  __shared__ __align__(16) u16 sKlo[BK * DD];
  __shared__ __align__(16) u16 sVt [DD * BK];     // V transposed: [d][key]
  __shared__ __align__(16) u16 sP  [4][16 * BK];  // per-wave P tile [qrow][key]

  const int tile = blockIdx.x;
  const int h    = blockIdx.y;

  // ---- map tile -> (segment, local q-tile) using cu_seqlens ----
  int seg = -1, row0 = 0, sbeg = 0, send = 0;
  {
    int acc = 0;
    for (int s = 0; s < nseq; ++s) {
      int b = cu[s], e = cu[s + 1];
      int nt = (e - b + BQ - 1) >> 6;
      if (seg < 0 && tile < acc + nt) {
        seg = s;
        int local = tile - acc;
        row0 = b + local * BQ; sbeg = b; send = e;
      }
      acc += nt;
    }
  }
  if (seg < 0) return;
  const int rows = min(BQ, send - row0);

  const int tid  = threadIdx.x;
  const int wv   = tid >> 6;        // wave id 0..3, owns q rows [wv*16, wv*16+16)
  const int lane = tid & 63;
  const int g    = lane >> 4;       // lane group 0..3
  const int c    = lane & 15;

  // ---- load Q fragments (A-layout: row=c, k=w*32+8g+e), scale+log2e, hi/lo split ----
  const float SC = 8.0f * 1.4426950408889634f;   // sqrt(D) * log2(e)
  bf16x8 qhi[2], qlo[2];
  {
    const int  qrl = wv * 16 + c;
    const bool qok = qrl < rows;
    const float* qp = q + ((size_t)h * T + (row0 + qrl)) * DD;
    for (int w = 0; w < 2; ++w) {
      int d0 = w * 32 + g * 8;
      float f[8];
      if (qok) {
        float4 a = *reinterpret_cast<const float4*>(qp + d0);
        float4 b = *reinterpret_cast<const float4*>(qp + d0 + 4);
        f[0]=a.x; f[1]=a.y; f[2]=a.z; f[3]=a.w;
        f[4]=b.x; f[5]=b.y; f[6]=b.z; f[7]=b.w;
      } else {
        for (int i = 0; i < 8; ++i) f[i] = 0.f;
      }
      for (int i = 0; i < 8; ++i) {
        float s  = f[i] * SC;
        u16   hb = f2bf(s);
        float hf = __uint_as_float(((uint32_t)hb) << 16);
        u16   lb = f2bf(s - hf);
        qhi[w][i] = (short)hb;
        qlo[w][i] = (short)lb;
      }
    }
  }

  f32x4 zero4 = {0.f, 0.f, 0.f, 0.f};
  f32x4 oacc[4];
  for (int dt = 0; dt < 4; ++dt) oacc[dt] = zero4;
  float mrun[4], lrun[4];
  for (int j = 0; j < 4; ++j) { mrun[j] = -1e30f; lrun[j] = 0.f; }

  for (int kt0 = sbeg; kt0 < send; kt0 += BK) {
    // ---- stage K(hi/lo) and V^T into LDS (fp32 -> bf16 convert) ----
    for (int p = 0; p < 4; ++p) {
      int key = p * 16 + (tid >> 4);
      int d0  = (tid & 15) * 4;
      int gk  = kt0 + key;
      float4 kv = {0,0,0,0}, vv = {0,0,0,0};
      if (gk < send) {
        kv = *reinterpret_cast<const float4*>(k + ((size_t)h * T + gk) * DD + d0);
        vv = *reinterpret_cast<const float4*>(v + ((size_t)h * T + gk) * DD + d0);
      }
      float kf[4] = {kv.x, kv.y, kv.z, kv.w};
      u16x4 hi4, lo4;
      for (int i = 0; i < 4; ++i) {
        u16   hb = f2bf(kf[i]);
        float hf = __uint_as_float(((uint32_t)hb) << 16);
        hi4[i] = hb;
        lo4[i] = f2bf(kf[i] - hf);
      }
      int kidx = (key * 64 + d0) ^ ((key & 7) << 3);
      *reinterpret_cast<u16x4*>(sKhi + kidx) = hi4;
      *reinterpret_cast<u16x4*>(sKlo + kidx) = lo4;
      float vf[4] = {vv.x, vv.y, vv.z, vv.w};
      for (int i = 0; i < 4; ++i) {
        int d = d0 + i;
        sVt[(d * 64 + key) ^ ((d & 7) << 3)] = f2bf(vf[i]);
      }
    }
    __syncthreads();

    // ---- S = Q'(scaled) · K^T  (hi*hi + hi*lo + lo*hi) ----
    f32x4 sacc[4];
    for (int kt = 0; kt < 4; ++kt) sacc[kt] = zero4;
    for (int kt = 0; kt < 4; ++kt) {
      int krow = kt * 16 + c;
      bf16x8 kh0 = ldsw8(sKhi, krow,      g * 8);
      bf16x8 kh1 = ldsw8(sKhi, krow, 32 + g * 8);
      bf16x8 kl0 = ldsw8(sKlo, krow,      g * 8);
      bf16x8 kl1 = ldsw8(sKlo, krow, 32 + g * 8);
      sacc[kt] = __builtin_amdgcn_mfma_f32_16x16x32_bf16(qhi[0], kh0, sacc[kt], 0, 0, 0);
      sacc[kt] = __builtin_amdgcn_mfma_f32_16x16x32_bf16(qhi[1], kh1, sacc[kt], 0, 0, 0);
      sacc[kt] = __builtin_amdgcn_mfma_f32_16x16x32_bf16(qlo[0], kh0, sacc[kt], 0, 0, 0);
      sacc[kt] = __builtin_amdgcn_mfma_f32_16x16x32_bf16(qlo[1], kh1, sacc[kt], 0, 0, 0);
      sacc[kt] = __builtin_amdgcn_mfma_f32_16x16x32_bf16(qhi[0], kl0, sacc[kt], 0, 0, 0);
      sacc[kt] = __builtin_amdgcn_mfma_f32_16x16x32_bf16(qhi[1], kl1, sacc[kt], 0, 0, 0);
    }

    // ---- mask invalid keys of a partial tile ----
    if (kt0 + BK > send) {
      for (int kt = 0; kt < 4; ++kt) {
        int gk = kt0 + kt * 16 + c;
        if (gk >= send) {
          sacc[kt][0] = -3.0e38f; sacc[kt][1] = -3.0e38f;
          sacc[kt][2] = -3.0e38f; sacc[kt][3] = -3.0e38f;
        }
      }
    }

    // ---- online softmax (exp2 domain) ----
    float mrow[4];
    for (int j = 0; j < 4; ++j)
      mrow[j] = fmaxf(fmaxf(sacc[0][j], sacc[1][j]), fmaxf(sacc[2][j], sacc[3][j]));
    for (int off = 1; off < 16; off <<= 1)
      for (int j = 0; j < 4; ++j)
        mrow[j] = fmaxf(mrow[j], __shfl_xor(mrow[j], off, 64));

    float alpha[4];
    for (int j = 0; j < 4; ++j) {
      float mn = fmaxf(mrun[j], mrow[j]);
      alpha[j] = exp2f(mrun[j] - mn);
      mrun[j] = mn;
    }

    float lrow[4] = {0.f, 0.f, 0.f, 0.f};
    u16* pb = sP[wv];
    for (int kt = 0; kt < 4; ++kt) {
      int key = kt * 16 + c;
      for (int j = 0; j < 4; ++j) {
        float pv = exp2f(sacc[kt][j] - mrun[j]);
        lrow[j] += pv;
        int row = g * 4 + j;
        pb[(row * 64 + key) ^ ((row & 7) << 3)] = f2bf(pv);
      }
    }
    for (int off = 1; off < 16; off <<= 1)
      for (int j = 0; j < 4; ++j)
        lrow[j] += __shfl_xor(lrow[j], off, 64);
    for (int j = 0; j < 4; ++j) lrun[j] = lrun[j] * alpha[j] + lrow[j];
    for (int dt = 0; dt < 4; ++dt)
      for (int j = 0; j < 4; ++j) oacc[dt][j] *= alpha[j];

    __syncthreads();   // cross-lane visibility of P (and keeps waves in phase)

    // ---- O += P · V ----
    bf16x8 pf0 = ldsw8(pb, c,      g * 8);
    bf16x8 pf1 = ldsw8(pb, c, 32 + g * 8);
    for (int dt = 0; dt < 4; ++dt) {
      bf16x8 v0 = ldsw8(sVt, dt * 16 + c,      g * 8);
      bf16x8 v1 = ldsw8(sVt, dt * 16 + c, 32 + g * 8);
      oacc[dt] = __builtin_amdgcn_mfma_f32_16x16x32_bf16(pf0, v0, oacc[dt], 0, 0, 0);
      oacc[dt] = __builtin_amdgcn_mfma_f32_16x16x32_bf16(pf1, v1, oacc[dt], 0, 0, 0);
    }
    __syncthreads();   // protect K/V/P LDS before next stage
  }

  // ---- epilogue: normalize and store [T,H,D] ----
  float inv[4];
  for (int j = 0; j < 4; ++j) inv[j] = 1.0f / lrun[j];
  for (int dt = 0; dt < 4; ++dt) {
    for (int j = 0; j < 4; ++j) {
      int rl = wv * 16 + g * 4 + j;
      if (rl < rows)
        out[((size_t)(row0 + rl) * HD + h) * DD + dt * 16 + c] = oacc[dt][j] * inv[j];
    }
  }
}

extern "C" void kernel_launch(void* const* d_in, const int* in_sizes, int n_in,
                              void* d_out, int out_size, void* d_ws, size_t ws_size,
                              hipStream_t stream) {
  const float* q  = (const float*)d_in[0];
  const float* k  = (const float*)d_in[1];
  const float* v  = (const float*)d_in[2];
  const int*   cu = (const int*)d_in[3];
  int nseq = in_sizes[3] - 1;
  int T    = in_sizes[0] / (HD * DD);
  int nqt  = T / BQ + nseq;            // upper bound incl. partial tiles
  dim3 grid(nqt, HD);
  fa_fwd<<<grid, dim3(256), 0, stream>>>(q, k, v, cu, (float*)d_out, T, nseq);
}